// Round 3
// baseline (1742.843 us; speedup 1.0000x reference)
//
#include <hip/hip_runtime.h>

#define SEQ   1024
#define BATCH 512
#define HID   128
#define GC    512   // 4 gates * HID

typedef __attribute__((ext_vector_type(8))) short          short8v;
typedef __attribute__((ext_vector_type(4))) float          float4v;
typedef __attribute__((ext_vector_type(2))) float          float2v;
typedef __attribute__((ext_vector_type(4))) unsigned short ushort4v;

__device__ __forceinline__ unsigned short f2bf(float f) {
    union { float f; unsigned u; } v; v.f = f;
    return (unsigned short)((v.u + 0x7fffu + ((v.u >> 16) & 1u)) >> 16);
}
__device__ __forceinline__ float bf2f(unsigned short u) {
    union { unsigned u; float f; } v; v.u = ((unsigned)u) << 16;
    return v.f;
}
__device__ __forceinline__ float fast_cos(float x) {
    return __builtin_amdgcn_cosf(x * 0.15915494309189535f);   // v_cos takes revolutions
}
__device__ __forceinline__ float fast_sigmoid(float x) {
    return __builtin_amdgcn_rcpf(1.0f + __builtin_amdgcn_exp2f(-1.4426950408889634f * x));
}
__device__ __forceinline__ float fast_tanh(float x) {
    return 1.0f - 2.0f * __builtin_amdgcn_rcpf(1.0f + __builtin_amdgcn_exp2f(2.8853900817779268f * x));
}

// raw barrier: drains LDS only; global prefetches stay in flight across it
#define BAR() do { asm volatile("s_waitcnt lgkmcnt(0)" ::: "memory");  \
                   __builtin_amdgcn_s_barrier();                       \
                   __builtin_amdgcn_sched_barrier(0); } while (0)

// ---------------------------------------------------------------------------
// GEMM prepass: Z[row][col] = bf16( X[row][:] @ Wgate[0:128][col-in-gate] + b )
// row = chunk-local (t*BATCH + b). 8 waves/WG; wave w -> Z cols [w*64,w*64+64).
// WG covers 128 rows. A = W frags (regs), B = X rows (16 N-slots, loaded
// k-contiguous straight from global; no LDS at all).
// ---------------------------------------------------------------------------
__global__ __launch_bounds__(512, 4) void qlstm_xgemm(
    const float* __restrict__ X,
    const float* __restrict__ Wf, const float* __restrict__ bfp,
    const float* __restrict__ Wi, const float* __restrict__ bip,
    const float* __restrict__ Wg, const float* __restrict__ bgp,
    const float* __restrict__ Wo, const float* __restrict__ bop,
    unsigned short* __restrict__ Z)
{
    const int tid = threadIdx.x, lane = tid & 63, wid = tid >> 6;
    const int l15 = lane & 15, kg = lane >> 4;
    const int g = wid >> 1;
    const float* Wsel = (g == 0) ? Wf : (g == 1) ? Wi : (g == 2) ? Wg : Wo;
    const float* bsel = (g == 0) ? bfp : (g == 1) ? bip : (g == 2) ? bgp : bop;
    const int cb  = (wid & 1) * 64;   // col base within gate
    const int zcb = wid * 64;         // col base within Z row

    short8v aw[4][4];                 // 64 VGPRs: W[k=0..127][cb+mt*16+l15]
    #pragma unroll
    for (int mt = 0; mt < 4; ++mt) {
        const int col = cb + mt * 16 + l15;
        #pragma unroll
        for (int ks = 0; ks < 4; ++ks) {
            const int k0 = ks * 32 + kg * 8;
            short8v a;
            #pragma unroll
            for (int j = 0; j < 8; ++j)
                a[j] = (short)f2bf(Wsel[(size_t)(k0 + j) * HID + col]);
            aw[mt][ks] = a;
        }
    }

    const int rowbase = blockIdx.x * 128;
    #pragma unroll 2
    for (int rg = 0; rg < 8; ++rg) {
        const int row = rowbase + rg * 16 + l15;
        const float* xb = X + (size_t)row * HID;
        short8v bx[4];
        #pragma unroll
        for (int ks = 0; ks < 4; ++ks) {
            float4v x0 = *(const float4v*)(xb + ks * 32 + kg * 8);
            float4v x1 = *(const float4v*)(xb + ks * 32 + kg * 8 + 4);
            short8v b;
            #pragma unroll
            for (int j = 0; j < 4; ++j) { b[j] = (short)f2bf(x0[j]); b[4 + j] = (short)f2bf(x1[j]); }
            bx[ks] = b;
        }
        float4v acc[4];
        #pragma unroll
        for (int mt = 0; mt < 4; ++mt)
            acc[mt] = *(const float4v*)(bsel + cb + mt * 16 + kg * 4);   // bias init (L1-hot)
        #pragma unroll
        for (int ks = 0; ks < 4; ++ks)
            #pragma unroll
            for (int mt = 0; mt < 4; ++mt)
                acc[mt] = __builtin_amdgcn_mfma_f32_16x16x32_bf16(aw[mt][ks], bx[ks], acc[mt], 0, 0, 0);
        #pragma unroll
        for (int mt = 0; mt < 4; ++mt) {
            ushort4v o;
            #pragma unroll
            for (int j = 0; j < 4; ++j) o[j] = f2bf(acc[mt][j]);
            *(ushort4v*)&Z[(size_t)row * GC + zcb + mt * 16 + kg * 4] = o;
        }
    }
}

// ---------------------------------------------------------------------------
// Recurrent kernel: 256 WGs x 512 thr, 2 batch rows/WG, 2 barriers/step.
// Phase A (8 waves): preact = Z[t] + h @ Wh  (MFMA, K=128, weights in regs).
// Phase C (waves 0-1): lane owns 2 adjacent cols of one row; all activations,
// single-wave cumprod scan, cell update, h_bf + out write.
// ---------------------------------------------------------------------------
__global__ __launch_bounds__(512, 4) void qlstm_rec(
    const unsigned short* __restrict__ Z,   // [chunk][BATCH][GC] bf16
    const float* __restrict__ Wf, const float* __restrict__ Wi,
    const float* __restrict__ Wg, const float* __restrict__ Wo,
    float* __restrict__ out,                // full [SEQ+2][BATCH][HID] base
    unsigned short* __restrict__ hstate,    // bf16 [BATCH][HID]
    float* __restrict__ cstate,             // f32  [BATCH][HID]
    int t0, int chunk, int last)
{
    __shared__ float preact[2][GC];
    __shared__ alignas(16) unsigned short h_bf[2][HID];

    const int tid = threadIdx.x, lane = tid & 63, wid = tid >> 6;
    const int l15 = lane & 15, kg = lane >> 4;
    const int row0 = blockIdx.x * 2;
    const int nn  = (l15 < 2) ? l15 : 1;
    const bool act = (l15 < 2);
    const int g = wid >> 1;
    const float* Wsel = (g == 0) ? Wf : (g == 1) ? Wi : (g == 2) ? Wg : Wo;
    const int cb  = (wid & 1) * 64;
    const int zcb = wid * 64;

    short8v aw[4][4];                 // 64 VGPRs: W[k=128..255][cb+mt*16+l15]
    #pragma unroll
    for (int mt = 0; mt < 4; ++mt) {
        const int col = cb + mt * 16 + l15;
        #pragma unroll
        for (int ks = 0; ks < 4; ++ks) {
            const int k0 = 128 + ks * 32 + kg * 8;
            short8v a;
            #pragma unroll
            for (int j = 0; j < 8; ++j)
                a[j] = (short)f2bf(Wsel[(size_t)(k0 + j) * HID + col]);
            aw[mt][ks] = a;
        }
    }

    if (tid < 256)
        h_bf[tid >> 7][tid & 127] = hstate[(size_t)(row0 + (tid >> 7)) * HID + (tid & 127)];
    float c0 = 0.f, c1 = 0.f, hL0 = 0.f, hL1 = 0.f;
    if (wid < 2) {
        c0 = cstate[(size_t)(row0 + wid) * HID + 2 * lane];
        c1 = cstate[(size_t)(row0 + wid) * HID + 2 * lane + 1];
    }

    ushort4v zpre[4];
    {
        const unsigned short* zb = Z + ((size_t)(row0 + nn)) * GC + zcb;
        #pragma unroll
        for (int mt = 0; mt < 4; ++mt) zpre[mt] = *(const ushort4v*)&zb[mt * 16 + kg * 4];
    }

    BAR();

    for (int t = 0; t < chunk; ++t) {
        // ---- Phase A: all 8 waves ----
        short8v bh[4];
        #pragma unroll
        for (int ks = 0; ks < 4; ++ks)
            bh[ks] = *(const short8v*)&h_bf[nn][ks * 32 + kg * 8];

        float4v acc[4];
        #pragma unroll
        for (int mt = 0; mt < 4; ++mt) {
            float4v a;
            #pragma unroll
            for (int j = 0; j < 4; ++j) a[j] = bf2f(zpre[mt][j]);
            acc[mt] = a;
        }
        {   // prefetch Z[t+1] (flies across both barriers)
            const int tn = (t + 1 < chunk) ? (t + 1) : t;
            const unsigned short* zb = Z + ((size_t)tn * BATCH + row0 + nn) * GC + zcb;
            #pragma unroll
            for (int mt = 0; mt < 4; ++mt) zpre[mt] = *(const ushort4v*)&zb[mt * 16 + kg * 4];
        }
        #pragma unroll
        for (int ks = 0; ks < 4; ++ks)
            #pragma unroll
            for (int mt = 0; mt < 4; ++mt)
                acc[mt] = __builtin_amdgcn_mfma_f32_16x16x32_bf16(aw[mt][ks], bh[ks], acc[mt], 0, 0, 0);

        if (act) {
            #pragma unroll
            for (int mt = 0; mt < 4; ++mt)
                *(float4v*)&preact[l15][zcb + mt * 16 + kg * 4] = acc[mt];
        }
        BAR();  // S1: preact ready

        // ---- Phase C: waves 0-1 only; lane owns cols {2*lane, 2*lane+1} of row wid
        if (wid < 2) {
            const int r = wid, ci = 2 * lane;
            float2v pf = *(const float2v*)&preact[r][0 * HID + ci];
            float2v pi = *(const float2v*)&preact[r][1 * HID + ci];
            float2v pg = *(const float2v*)&preact[r][2 * HID + ci];
            float2v po = *(const float2v*)&preact[r][3 * HID + ci];

            // f-gate: inclusive cumprod of cos over 128 cols, 2 cols/lane
            const float fc0 = fast_cos(pf[0]), fc1 = fast_cos(pf[1]);
            const float p = fc0 * fc1;
            float P = p;
            #pragma unroll
            for (int d = 1; d < 64; d <<= 1) {
                float q = __shfl_up(P, d);
                if (lane >= d) P *= q;
            }
            float Pex = __shfl_up(P, 1);
            if (lane == 0) Pex = 1.f;
            const float f0 = (Pex * fc0 + 1.f) * 0.5f;
            const float f1 = (Pex * p   + 1.f) * 0.5f;

            const float i0 = (fast_cos(pi[0]) + 1.f) * 0.5f;
            const float i1 = (fast_cos(pi[1]) + 1.f) * 0.5f;
            const float g0 = fast_tanh(pg[0]);
            const float g1 = fast_tanh(pg[1]);
            const float o0 = fast_sigmoid(po[0]);
            const float o1 = fast_sigmoid(po[1]);

            const float cn0 = fmaf(f0, c0, i0 * g0);
            const float cn1 = fmaf(f1, c1, i1 * g1);
            const float hn0 = o0 * fast_tanh(cn0);
            const float hn1 = o1 * fast_tanh(cn1);
            c0 = cn0; c1 = cn1; hL0 = hn0; hL1 = hn1;

            *(unsigned*)&h_bf[r][ci] = (unsigned)f2bf(hn0) | ((unsigned)f2bf(hn1) << 16);
            float2v ov; ov[0] = hn0; ov[1] = hn1;
            *(float2v*)&out[((size_t)(t0 + t) * BATCH + row0 + r) * HID + ci] = ov;
        }
        BAR();  // S2: h ready for next step
    }

    // save state for next chunk
    if (tid < 256)
        hstate[(size_t)(row0 + (tid >> 7)) * HID + (tid & 127)] = h_bf[tid >> 7][tid & 127];
    if (wid < 2) {
        cstate[(size_t)(row0 + wid) * HID + 2 * lane]     = c0;
        cstate[(size_t)(row0 + wid) * HID + 2 * lane + 1] = c1;
        if (last) {   // final hx, cx tail (f32, exact copies of last-step values)
            const size_t base = (size_t)SEQ * BATCH * HID;
            const size_t ro = (size_t)(row0 + wid) * HID + 2 * lane;
            out[base + ro]     = hL0;
            out[base + ro + 1] = hL1;
            out[base + (size_t)BATCH * HID + ro]     = c0;
            out[base + (size_t)BATCH * HID + ro + 1] = c1;
        }
    }
}

// ---------------------------------------------------------------------------
extern "C" void kernel_launch(void* const* d_in, const int* in_sizes, int n_in,
                              void* d_out, int out_size, void* d_ws, size_t ws_size,
                              hipStream_t stream) {
    const float* X  = (const float*)d_in[0];
    const float* Wf = (const float*)d_in[1];
    const float* bf = (const float*)d_in[2];
    const float* Wi = (const float*)d_in[3];
    const float* bi = (const float*)d_in[4];
    const float* Wg = (const float*)d_in[5];
    const float* bg = (const float*)d_in[6];
    const float* Wo = (const float*)d_in[7];
    const float* bo = (const float*)d_in[8];
    float* out = (float*)d_out;

    char* ws = (char*)d_ws;
    unsigned short* hstate = (unsigned short*)ws;                 // 128 KB
    float*          cstate = (float*)(ws + 256 * 1024);           // 256 KB
    unsigned short* Zbuf   = (unsigned short*)(ws + 1024 * 1024);

    const size_t zstep = (size_t)BATCH * GC * sizeof(unsigned short);  // 512 KB/step
    size_t zcap = (ws_size > (1u << 20)) ? ws_size - (1u << 20) : 0;
    int Tc = (int)(zcap / zstep);
    if (Tc > SEQ) Tc = SEQ;
    if (Tc < 1)   Tc = 1;

    hipMemsetAsync(ws, 0, 1024 * 1024, stream);   // zero h/c state

    for (int t0 = 0; t0 < SEQ; t0 += Tc) {
        const int chunk = (SEQ - t0 < Tc) ? (SEQ - t0) : Tc;
        qlstm_xgemm<<<chunk * BATCH / 128, 512, 0, stream>>>(
            X + (size_t)t0 * BATCH * HID,
            Wf, bf, Wi, bi, Wg, bg, Wo, bo, Zbuf);
        qlstm_rec<<<BATCH / 2, 512, 0, stream>>>(
            Zbuf, Wf, Wi, Wg, Wo, out, hstate, cstate,
            t0, chunk, (t0 + chunk == SEQ) ? 1 : 0);
    }
}